// Round 14
// baseline (174.405 us; speedup 1.0000x reference)
//
#include <hip/hip_runtime.h>

#define N_NODES 100000
#define MPAD    100096   // 782*128
#define F_IN 128
#define HID 256
#define C_OUT 50
#define N_EDGES 640000
#define CAP 32           // per-node bucket capacity (max degree ~22)
#define NRANGE 391       // ceil(N/256) node ranges of 256
#define P1BLK 256        // phase-1 blocks
#define EPB (N_EDGES / P1BLK)   // 2500 edges per phase-1 block
#define CCAP 32          // per (range, block) cell capacity (mean 6.4)
#define XBLK 12500       // xcvt blocks
#define WBLK 256         // weight-pack blocks

typedef __attribute__((ext_vector_type(8))) short short8;
typedef __attribute__((ext_vector_type(8))) ushort us8;
typedef __attribute__((ext_vector_type(4))) float f32x4;

struct alignas(8) us4 { ushort x, y, z, w; };

__device__ __forceinline__ ushort f2bf(float f) {
    union { float f; unsigned u; } v; v.f = f;
    unsigned r = (v.u + 0x7fffu + ((v.u >> 16) & 1u)) >> 16;  // RNE
    return (ushort)r;
}

__device__ __forceinline__ float bf2f(ushort u) {
    union { unsigned u; float f; } v; v.u = ((unsigned)u) << 16;
    return v.f;
}

__device__ __forceinline__ void load_lds16(const void* gsrc, void* lds) {
    __builtin_amdgcn_global_load_lds(
        (const __attribute__((address_space(1))) void*)gsrc,
        (__attribute__((address_space(3))) void*)lds, 16, 0, 0);
}

// ---------------- fused: edge phase 1 || xcvt || weight pack ----------------
// blocks [0,256): bin edges into subbucket cells via PRIVATE LDS cursors (no global atomics)
// blocks [256, 256+12500): x -> bf16 into A1 cols 128..255
// blocks [256+12500, +256): pack weights to bf16
__global__ __launch_bounds__(256) void phase1_xcvt(const int* __restrict__ src,
                                                   const int* __restrict__ dst,
                                                   int* __restrict__ cnt1,
                                                   int* __restrict__ subbucket,
                                                   const float* __restrict__ x,
                                                   ushort* __restrict__ A1,
                                                   const float* __restrict__ W1l,
                                                   const float* __restrict__ W1r,
                                                   const float* __restrict__ W2l,
                                                   const float* __restrict__ W2r,
                                                   ushort* __restrict__ B1t,
                                                   ushort* __restrict__ B2t) {
    __shared__ int lcnt[NRANGE];
    int b = blockIdx.x;
    if (b < P1BLK) {
        for (int r = threadIdx.x; r < NRANGE; r += 256) lcnt[r] = 0;
        __syncthreads();
        int base = b * EPB;
        for (int i = base + (int)threadIdx.x; i < base + EPB; i += 256) {
            int d = dst[i];
            int s = src[i];
            int r = d >> 8;
            int p = atomicAdd(&lcnt[r], 1);
            if (p < CCAP) subbucket[((size_t)r * P1BLK + b) * CCAP + p] = ((d & 255) << 24) | s;
        }
        __syncthreads();
        for (int r = threadIdx.x; r < NRANGE; r += 256) cnt1[r * P1BLK + b] = lcnt[r];
    } else if (b < P1BLK + XBLK) {
        int tid = (b - P1BLK) * 256 + threadIdx.x;
        int node = tid >> 5, q = tid & 31;
        if (node >= N_NODES) return;
        float4 v = *reinterpret_cast<const float4*>(x + (size_t)node * F_IN + q * 4);
        us4 o;
        o.x = f2bf(v.x); o.y = f2bf(v.y); o.z = f2bf(v.z); o.w = f2bf(v.w);
        *reinterpret_cast<us4*>(&A1[(size_t)node * 256 + 128 + q * 4]) = o;
    } else {
        int idx = (b - P1BLK - XBLK) * 256 + threadIdx.x;
        if (idx < 256 * 256) {
            int o = idx >> 8, k = idx & 255;
            float v = (k < 128) ? W1l[o * 128 + k] : W1r[o * 128 + (k - 128)];
            B1t[o * 256 + k] = f2bf(v);
        }
        if (idx < 128 * 256) {
            int c = idx >> 8, k = idx & 255;
            float v = 0.f;
            if (c < C_OUT) v = W2l[c * 256 + k];
            else if (c >= 64 && c < 64 + C_OUT) v = W2r[(c - 64) * 256 + k];
            B2t[c * 256 + k] = f2bf(v);
        }
    }
}

// ---------------- edge phase 2: merge cells -> per-node buckets (coalesced out) ----------------
__global__ __launch_bounds__(256) void phase2_merge(const int* __restrict__ cnt1,
                                                    const int* __restrict__ subbucket,
                                                    int* __restrict__ cnt,
                                                    int* __restrict__ bucket) {
    __shared__ int lcnt2[256];
    __shared__ int lbuf[256 * CAP];  // 32 KB
    int r = blockIdx.x, t = threadIdx.x;
    lcnt2[t] = 0;
    __syncthreads();
    int n = cnt1[r * P1BLK + t];
    if (n > CCAP) n = CCAP;
    size_t cbase = ((size_t)r * P1BLK + t) * CCAP;
    for (int k = 0; k < n; ++k) {
        unsigned u = (unsigned)subbucket[cbase + k];
        int dl = u >> 24;
        int p = atomicAdd(&lcnt2[dl], 1);
        if (p < CAP) lbuf[dl * CAP + p] = (int)(u & 0xFFFFFF);
    }
    __syncthreads();
    int node0 = r << 8;
    if (node0 + t < N_NODES) cnt[node0 + t] = lcnt2[t];
    for (int idx = t; idx < 256 * CAP; idx += 256) {
        if (node0 + (idx >> 5) < N_NODES) bucket[(size_t)node0 * CAP + idx] = lbuf[idx];
    }
}

// ---------------- fused GEMM1 + gather: h = relu([agg|x] @ B1t^T + b1l) ----------------
// 512 threads = 8 waves (2 row x 4 col), acc[4][4] per wave (no register cliff).
// As holds ONE K-half [4][128][32] (32 KB); Bs [256][32] (16 KB) -> 48 KB -> 3 blocks/CU.
// Half 1: gather agg (K=0..127) in-block, MFMA kt=0..3; half 2: copy self-x, MFMA kt=4..7.
__global__ __launch_bounds__(512) void gemm1_gather(
    const ushort* __restrict__ A1, const int* __restrict__ cnt,
    const int* __restrict__ bucket, const ushort* __restrict__ B,
    const float* __restrict__ bias, ushort* __restrict__ hOut) {
    __shared__ alignas(16) ushort As[4 * 128 * 32];  // 32 KB, [kt][row][32]
    __shared__ alignas(16) ushort Bs[256 * 32];      // 16 KB
    const int tid = threadIdx.x;
    const int lane = tid & 63, wid = tid >> 6;
    const int wr = wid >> 2, wc = wid & 3;           // 2 x 4 waves
    const int brow = blockIdx.x;
    const int aoffA = (lane & 15) * 32 + (lane >> 4) * 8;

    // ---- phase A: aggregate neighbors -> As (K = 0..127) ----
#pragma unroll
    for (int uu = 0; uu < 4; ++uu) {
        int u = tid + uu * 512;           // 2048 units = 128 rows x 16 q-slices
        int r = u >> 4, q = u & 15;
        int node = brow * 128 + r;
        float a[8];
#pragma unroll
        for (int j = 0; j < 8; ++j) a[j] = 0.f;
        if (node < N_NODES) {
            int n = cnt[node];
            if (n > CAP) n = CAP;
            const int* row = bucket + (size_t)node * CAP;
            int p = 0;
            while (p + 8 <= n) {
                us8 v[8];
#pragma unroll
                for (int t = 0; t < 8; ++t) {
                    int s = row[p + t];
                    v[t] = *reinterpret_cast<const us8*>(&A1[(size_t)s * 256 + 128 + q * 8]);
                }
#pragma unroll
                for (int t = 0; t < 8; ++t)
#pragma unroll
                    for (int j = 0; j < 8; ++j) a[j] += bf2f(v[t][j]);
                p += 8;
            }
            int rem = n - p;
            if (rem > 0) {
                us8 v[7];
#pragma unroll
                for (int t = 0; t < 7; ++t) {
                    int s = (t < rem) ? row[p + t] : row[p];
                    v[t] = *reinterpret_cast<const us8*>(&A1[(size_t)s * 256 + 128 + q * 8]);
                }
#pragma unroll
                for (int t = 0; t < 7; ++t) {
                    if (t < rem) {
#pragma unroll
                        for (int j = 0; j < 8; ++j) a[j] += bf2f(v[t][j]);
                    }
                }
            }
        }
        us8 o;
#pragma unroll
        for (int j = 0; j < 8; ++j) o[j] = f2bf(a[j]);
        *reinterpret_cast<us8*>(&As[(q >> 2) * 4096 + r * 32 + (q & 3) * 8]) = o;
    }
    __syncthreads();

    f32x4 acc[4][4];
#pragma unroll
    for (int m = 0; m < 4; ++m)
#pragma unroll
        for (int n = 0; n < 4; ++n) acc[m][n] = (f32x4){0.f, 0.f, 0.f, 0.f};

    const int rB0 = tid >> 2, kB0 = (tid & 3) * 8;
    const int cB1 = tid + 512;
    const int rB1 = cB1 >> 2, kB1 = (cB1 & 3) * 8;

    // ---- K half 1: kt = 0..3 (agg) ----
    for (int kt = 0; kt < 4; ++kt) {
        const int kOff = kt * 32;
        load_lds16(B + (size_t)rB0 * 256 + kOff + kB0, &Bs[tid * 8]);
        load_lds16(B + (size_t)rB1 * 256 + kOff + kB1, &Bs[cB1 * 8]);
        __syncthreads();
        short8 af[4], bfr[4];
#pragma unroll
        for (int m = 0; m < 4; ++m)
            af[m] = *reinterpret_cast<const short8*>(&As[kt * 4096 + (wr * 64 + m * 16) * 32 + aoffA]);
#pragma unroll
        for (int n = 0; n < 4; ++n)
            bfr[n] = *reinterpret_cast<const short8*>(&Bs[(wc * 64 + n * 16) * 32 + aoffA]);
#pragma unroll
        for (int m = 0; m < 4; ++m)
#pragma unroll
            for (int n = 0; n < 4; ++n)
                acc[m][n] = __builtin_amdgcn_mfma_f32_16x16x32_bf16(af[m], bfr[n], acc[m][n], 0, 0, 0);
        __syncthreads();
    }

    // ---- phase A2: self x -> As (K = 128..255) ----
#pragma unroll
    for (int uu = 0; uu < 4; ++uu) {
        int u = tid + uu * 512;
        int r = u >> 4, q = u & 15;
        int node = brow * 128 + r;
        us8 xv;
        if (node < N_NODES) {
            xv = *reinterpret_cast<const us8*>(&A1[(size_t)node * 256 + 128 + q * 8]);
        } else {
#pragma unroll
            for (int j = 0; j < 8; ++j) xv[j] = 0;
        }
        *reinterpret_cast<us8*>(&As[(q >> 2) * 4096 + r * 32 + (q & 3) * 8]) = xv;
    }
    __syncthreads();

    // ---- K half 2: kt = 4..7 (x) ----
    for (int kt = 4; kt < 8; ++kt) {
        const int kOff = kt * 32;
        load_lds16(B + (size_t)rB0 * 256 + kOff + kB0, &Bs[tid * 8]);
        load_lds16(B + (size_t)rB1 * 256 + kOff + kB1, &Bs[cB1 * 8]);
        __syncthreads();
        short8 af[4], bfr[4];
#pragma unroll
        for (int m = 0; m < 4; ++m)
            af[m] = *reinterpret_cast<const short8*>(&As[(kt - 4) * 4096 + (wr * 64 + m * 16) * 32 + aoffA]);
#pragma unroll
        for (int n = 0; n < 4; ++n)
            bfr[n] = *reinterpret_cast<const short8*>(&Bs[(wc * 64 + n * 16) * 32 + aoffA]);
#pragma unroll
        for (int m = 0; m < 4; ++m)
#pragma unroll
            for (int n = 0; n < 4; ++n)
                acc[m][n] = __builtin_amdgcn_mfma_f32_16x16x32_bf16(af[m], bfr[n], acc[m][n], 0, 0, 0);
        __syncthreads();
    }

    const int colB = wc * 64 + (lane & 15);
    const int rowB = brow * 128 + wr * 64 + ((lane >> 4) << 2);

    float bv[4];
#pragma unroll
    for (int n = 0; n < 4; ++n) bv[n] = bias[colB + n * 16];
#pragma unroll
    for (int m = 0; m < 4; ++m) {
#pragma unroll
        for (int r = 0; r < 4; ++r) {
            int row = rowB + m * 16 + r;
            if (row >= N_NODES) continue;
#pragma unroll
            for (int n = 0; n < 4; ++n) {
                float v = acc[m][n][r] + bv[n];
                v = v > 0.f ? v : 0.f;
                hOut[(size_t)row * 256 + colB + n * 16] = f2bf(v);
            }
        }
    }
}

// ---------------- gather2: out[i] += sum_{s in N(i)} g[s] (g bf16, stride 64) ----------------
__global__ void gather2_kernel(const ushort* __restrict__ g, const int* __restrict__ cnt,
                               const int* __restrict__ bucket, float* __restrict__ out) {
    int tid = blockIdx.x * blockDim.x + threadIdx.x;
    int node = tid >> 3, q = tid & 7;
    if (node >= N_NODES) return;
    int c = q * 8;
    if (c >= C_OUT) return;
    int n = cnt[node];
    if (n > CAP) n = CAP;
    const int* row = bucket + (size_t)node * CAP;
    float a[8];
#pragma unroll
    for (int j = 0; j < 8; ++j) a[j] = 0.f;
    int p = 0;
    while (p + 8 <= n) {
        us8 v[8];
#pragma unroll
        for (int t = 0; t < 8; ++t) {
            int s = row[p + t];
            v[t] = *reinterpret_cast<const us8*>(&g[(size_t)s * 64 + c]);
        }
#pragma unroll
        for (int t = 0; t < 8; ++t)
#pragma unroll
            for (int j = 0; j < 8; ++j) a[j] += bf2f(v[t][j]);
        p += 8;
    }
    int rem = n - p;
    if (rem > 0) {
        us8 v[7];
#pragma unroll
        for (int t = 0; t < 7; ++t) {
            int s = (t < rem) ? row[p + t] : row[p];
            v[t] = *reinterpret_cast<const us8*>(&g[(size_t)s * 64 + c]);
        }
#pragma unroll
        for (int t = 0; t < 7; ++t) {
            if (t < rem) {
#pragma unroll
                for (int j = 0; j < 8; ++j) a[j] += bf2f(v[t][j]);
            }
        }
    }
    float* po = out + (size_t)node * C_OUT;
#pragma unroll
    for (int j = 0; j < 8; ++j) {
        if (c + j < C_OUT) po[c + j] += a[j];
    }
}

// ---------------- GEMM2: [g(bf16,stride64) | out_pre] = h @ B2t^T (+b2l) ----------------
__global__ __launch_bounds__(256) void gemm2_kernel(
    const ushort* __restrict__ A, const ushort* __restrict__ B,
    const float* __restrict__ bias, ushort* __restrict__ gOut,
    float* __restrict__ oOut) {
    __shared__ alignas(16) ushort As[128 * 32];
    __shared__ alignas(16) ushort Bs[128 * 32];
    const int tid = threadIdx.x;
    const int lane = tid & 63, wid = tid >> 6;
    const int wr = wid >> 1, wc = wid & 1;
    const int brow = blockIdx.x;

    f32x4 acc[4][4];
#pragma unroll
    for (int m = 0; m < 4; ++m)
#pragma unroll
        for (int n = 0; n < 4; ++n) acc[m][n] = (f32x4){0.f, 0.f, 0.f, 0.f};

    const int c0 = tid, c1 = tid + 256;
    const int r0 = c0 >> 2, k80 = (c0 & 3) * 8;
    const int r1 = c1 >> 2, k81 = (c1 & 3) * 8;
    const size_t aRow0 = (size_t)(brow * 128 + r0) * 256;
    const size_t aRow1 = (size_t)(brow * 128 + r1) * 256;
    const size_t bRow0 = (size_t)r0 * 256;
    const size_t bRow1 = (size_t)r1 * 256;

    const int aoffA = (lane & 15) * 32 + (lane >> 4) * 8;

    for (int kt = 0; kt < 8; ++kt) {
        const int kOff = kt * 32;
        load_lds16(A + aRow0 + kOff + k80, &As[c0 * 8]);
        load_lds16(A + aRow1 + kOff + k81, &As[c1 * 8]);
        load_lds16(B + bRow0 + kOff + k80, &Bs[c0 * 8]);
        load_lds16(B + bRow1 + kOff + k81, &Bs[c1 * 8]);
        __syncthreads();

        short8 af[4], bfr[4];
#pragma unroll
        for (int m = 0; m < 4; ++m)
            af[m] = *reinterpret_cast<const short8*>(&As[(wr * 64 + m * 16) * 32 + aoffA]);
#pragma unroll
        for (int n = 0; n < 4; ++n)
            bfr[n] = *reinterpret_cast<const short8*>(&Bs[(wc * 64 + n * 16) * 32 + aoffA]);
#pragma unroll
        for (int m = 0; m < 4; ++m)
#pragma unroll
            for (int n = 0; n < 4; ++n)
                acc[m][n] = __builtin_amdgcn_mfma_f32_16x16x32_bf16(af[m], bfr[n], acc[m][n], 0, 0, 0);
        __syncthreads();
    }

    const int colB = wc * 64 + (lane & 15);
    const int rowB = brow * 128 + wr * 64 + ((lane >> 4) << 2);

#pragma unroll
    for (int m = 0; m < 4; ++m) {
#pragma unroll
        for (int r = 0; r < 4; ++r) {
            int row = rowB + m * 16 + r;
            if (row >= N_NODES) continue;
#pragma unroll
            for (int n = 0; n < 4; ++n) {
                int cg = colB + n * 16;
                float v = acc[m][n][r];
                if (cg < 64) {
                    gOut[(size_t)row * 64 + cg] = f2bf(v);
                } else if (cg < 64 + C_OUT) {
                    oOut[(size_t)row * C_OUT + (cg - 64)] = v + bias[cg - 64];
                }
            }
        }
    }
}

extern "C" void kernel_launch(void* const* d_in, const int* in_sizes, int n_in,
                              void* d_out, int out_size, void* d_ws, size_t ws_size,
                              hipStream_t stream) {
    const float* x   = (const float*)d_in[0];
    const int*   ei  = (const int*)d_in[1];
    const float* W1l = (const float*)d_in[2];
    const float* b1l = (const float*)d_in[3];
    const float* W1r = (const float*)d_in[4];
    const float* W2l = (const float*)d_in[5];
    const float* b2l = (const float*)d_in[6];
    const float* W2r = (const float*)d_in[7];
    float* out = (float*)d_out;

    ushort* A1    = (ushort*)d_ws;                        // MPAD*256 bf16 (right half used)
    ushort* hbuf  = A1 + (size_t)MPAD * 256;              // MPAD*256 bf16
    ushort* B1t   = hbuf + (size_t)MPAD * 256;            // 256*256 bf16
    ushort* B2t   = B1t + 256 * 256;                      // 128*256 bf16
    ushort* g     = B2t + 128 * 256;                      // N*64 bf16
    int* cnt      = (int*)(g + (size_t)N_NODES * 64);     // N
    int* bucket   = cnt + N_NODES;                        // N*CAP
    int* cnt1     = bucket + (size_t)N_NODES * CAP;       // NRANGE*P1BLK
    int* subbucket= cnt1 + NRANGE * P1BLK;                // NRANGE*P1BLK*CCAP

    const int* src = ei;
    const int* dst = ei + N_EDGES;

    phase1_xcvt<<<P1BLK + XBLK + WBLK, 256, 0, stream>>>(
        src, dst, cnt1, subbucket, x, A1, W1l, W1r, W2l, W2r, B1t, B2t);
    phase2_merge<<<NRANGE, 256, 0, stream>>>(cnt1, subbucket, cnt, bucket);

    const int nbrow = MPAD / 128;  // 782
    gemm1_gather<<<nbrow, 512, 0, stream>>>(A1, cnt, bucket, B1t, b1l, hbuf);
    gemm2_kernel<<<nbrow, 256, 0, stream>>>(hbuf, B2t, b2l, g, out);

    gather2_kernel<<<(N_NODES * 8 + 255) / 256, 256, 0, stream>>>(g, cnt, bucket, out);
}

// Round 15
// 147.428 us; speedup vs baseline: 1.1830x; 1.1830x over previous
//
#include <hip/hip_runtime.h>

#define N_NODES 100000
#define MPAD    100096   // 782*128
#define F_IN 128
#define HID 256
#define C_OUT 50
#define N_EDGES 640000
#define CAP 32           // per-node bucket capacity (max degree ~22)
#define NRANGE 391       // ceil(N/256) node ranges of 256
#define P1BLK 256        // phase-1 blocks
#define EPB (N_EDGES / P1BLK)   // 2500 edges per phase-1 block
#define CCAP 32          // per (range, block) cell capacity (mean 6.4)
#define XBLK 12500       // xcvt blocks
#define WBLK 256         // weight-pack blocks

typedef __attribute__((ext_vector_type(8))) short short8;
typedef __attribute__((ext_vector_type(8))) ushort us8;
typedef __attribute__((ext_vector_type(4))) float f32x4;

struct alignas(8) us4 { ushort x, y, z, w; };

__device__ __forceinline__ ushort f2bf(float f) {
    union { float f; unsigned u; } v; v.f = f;
    unsigned r = (v.u + 0x7fffu + ((v.u >> 16) & 1u)) >> 16;  // RNE
    return (ushort)r;
}

__device__ __forceinline__ float bf2f(ushort u) {
    union { unsigned u; float f; } v; v.u = ((unsigned)u) << 16;
    return v.f;
}

__device__ __forceinline__ void load_lds16(const void* gsrc, void* lds) {
    __builtin_amdgcn_global_load_lds(
        (const __attribute__((address_space(1))) void*)gsrc,
        (__attribute__((address_space(3))) void*)lds, 16, 0, 0);
}

// ---------------- fused: edge phase 1 || xcvt || weight pack ----------------
__global__ __launch_bounds__(256) void phase1_xcvt(const int* __restrict__ src,
                                                   const int* __restrict__ dst,
                                                   int* __restrict__ cnt1,
                                                   int* __restrict__ subbucket,
                                                   const float* __restrict__ x,
                                                   ushort* __restrict__ A1,
                                                   const float* __restrict__ W1l,
                                                   const float* __restrict__ W1r,
                                                   const float* __restrict__ W2l,
                                                   const float* __restrict__ W2r,
                                                   ushort* __restrict__ B1t,
                                                   ushort* __restrict__ B2t) {
    __shared__ int lcnt[NRANGE];
    int b = blockIdx.x;
    if (b < P1BLK) {
        for (int r = threadIdx.x; r < NRANGE; r += 256) lcnt[r] = 0;
        __syncthreads();
        int base = b * EPB;
        for (int i = base + (int)threadIdx.x; i < base + EPB; i += 256) {
            int d = dst[i];
            int s = src[i];
            int r = d >> 8;
            int p = atomicAdd(&lcnt[r], 1);
            if (p < CCAP) subbucket[((size_t)r * P1BLK + b) * CCAP + p] = ((d & 255) << 24) | s;
        }
        __syncthreads();
        for (int r = threadIdx.x; r < NRANGE; r += 256) cnt1[r * P1BLK + b] = lcnt[r];
    } else if (b < P1BLK + XBLK) {
        int tid = (b - P1BLK) * 256 + threadIdx.x;
        int node = tid >> 5, q = tid & 31;
        if (node >= N_NODES) return;
        float4 v = *reinterpret_cast<const float4*>(x + (size_t)node * F_IN + q * 4);
        us4 o;
        o.x = f2bf(v.x); o.y = f2bf(v.y); o.z = f2bf(v.z); o.w = f2bf(v.w);
        *reinterpret_cast<us4*>(&A1[(size_t)node * 256 + 128 + q * 4]) = o;
    } else {
        int idx = (b - P1BLK - XBLK) * 256 + threadIdx.x;
        if (idx < 256 * 256) {
            int o = idx >> 8, k = idx & 255;
            float v = (k < 128) ? W1l[o * 128 + k] : W1r[o * 128 + (k - 128)];
            B1t[o * 256 + k] = f2bf(v);
        }
        if (idx < 128 * 256) {
            int c = idx >> 8, k = idx & 255;
            float v = 0.f;
            if (c < C_OUT) v = W2l[c * 256 + k];
            else if (c >= 64 && c < 64 + C_OUT) v = W2r[(c - 64) * 256 + k];
            B2t[c * 256 + k] = f2bf(v);
        }
    }
}

// ---------------- edge phase 2: merge cells -> per-node buckets (coalesced out) ----------------
__global__ __launch_bounds__(256) void phase2_merge(const int* __restrict__ cnt1,
                                                    const int* __restrict__ subbucket,
                                                    int* __restrict__ cnt,
                                                    int* __restrict__ bucket) {
    __shared__ int lcnt2[256];
    __shared__ int lbuf[256 * CAP];  // 32 KB
    int r = blockIdx.x, t = threadIdx.x;
    lcnt2[t] = 0;
    __syncthreads();
    int n = cnt1[r * P1BLK + t];
    if (n > CCAP) n = CCAP;
    size_t cbase = ((size_t)r * P1BLK + t) * CCAP;
    for (int k = 0; k < n; ++k) {
        unsigned u = (unsigned)subbucket[cbase + k];
        int dl = u >> 24;
        int p = atomicAdd(&lcnt2[dl], 1);
        if (p < CAP) lbuf[dl * CAP + p] = (int)(u & 0xFFFFFF);
    }
    __syncthreads();
    int node0 = r << 8;
    if (node0 + t < N_NODES) cnt[node0 + t] = lcnt2[t];
    for (int idx = t; idx < 256 * CAP; idx += 256) {
        if (node0 + (idx >> 5) < N_NODES) bucket[(size_t)node0 * CAP + idx] = lbuf[idx];
    }
}

// ---------------- gather1: A1[i][0..127] = bf16( sum_{s in N(i)} bf16x[s] ) ----------------
// 8 lanes/node, 32 B/neighbor (2 x us8), 4-neighbor batches -> 8 loads in flight/lane
__global__ void gather1_kernel(const int* __restrict__ cnt, const int* __restrict__ bucket,
                               ushort* __restrict__ A1) {
    int tid = blockIdx.x * blockDim.x + threadIdx.x;
    int node = tid >> 3, q = tid & 7;
    if (node >= N_NODES) return;
    int n = cnt[node];
    if (n > CAP) n = CAP;
    const int* row = bucket + (size_t)node * CAP;
    float a[16];
#pragma unroll
    for (int j = 0; j < 16; ++j) a[j] = 0.f;
    int p = 0;
    while (p + 4 <= n) {
        us8 v0[4], v1[4];
#pragma unroll
        for (int t = 0; t < 4; ++t) {
            const ushort* base = &A1[(size_t)row[p + t] * 256 + 128 + q * 16];
            v0[t] = *reinterpret_cast<const us8*>(base);
            v1[t] = *reinterpret_cast<const us8*>(base + 8);
        }
#pragma unroll
        for (int t = 0; t < 4; ++t) {
#pragma unroll
            for (int j = 0; j < 8; ++j) a[j] += bf2f(v0[t][j]);
#pragma unroll
            for (int j = 0; j < 8; ++j) a[8 + j] += bf2f(v1[t][j]);
        }
        p += 4;
    }
    int rem = n - p;
    if (rem > 0) {
        us8 v0[3], v1[3];
#pragma unroll
        for (int t = 0; t < 3; ++t) {
            int s = (t < rem) ? row[p + t] : row[p];
            const ushort* base = &A1[(size_t)s * 256 + 128 + q * 16];
            v0[t] = *reinterpret_cast<const us8*>(base);
            v1[t] = *reinterpret_cast<const us8*>(base + 8);
        }
#pragma unroll
        for (int t = 0; t < 3; ++t) {
            if (t < rem) {
#pragma unroll
                for (int j = 0; j < 8; ++j) a[j] += bf2f(v0[t][j]);
#pragma unroll
                for (int j = 0; j < 8; ++j) a[8 + j] += bf2f(v1[t][j]);
            }
        }
    }
    us8 o0, o1;
#pragma unroll
    for (int j = 0; j < 8; ++j) { o0[j] = f2bf(a[j]); o1[j] = f2bf(a[8 + j]); }
    ushort* wbase = &A1[(size_t)node * 256 + q * 16];
    *reinterpret_cast<us8*>(wbase) = o0;
    *reinterpret_cast<us8*>(wbase + 8) = o1;
}

// ---------------- gather2: out[i] += sum_{s in N(i)} g[s] (g bf16, stride 64) ----------------
__global__ void gather2_kernel(const ushort* __restrict__ g, const int* __restrict__ cnt,
                               const int* __restrict__ bucket, float* __restrict__ out) {
    int tid = blockIdx.x * blockDim.x + threadIdx.x;
    int node = tid >> 3, q = tid & 7;
    if (node >= N_NODES) return;
    int c = q * 8;
    if (c >= C_OUT) return;
    int n = cnt[node];
    if (n > CAP) n = CAP;
    const int* row = bucket + (size_t)node * CAP;
    float a[8];
#pragma unroll
    for (int j = 0; j < 8; ++j) a[j] = 0.f;
    int p = 0;
    while (p + 8 <= n) {
        us8 v[8];
#pragma unroll
        for (int t = 0; t < 8; ++t) {
            int s = row[p + t];
            v[t] = *reinterpret_cast<const us8*>(&g[(size_t)s * 64 + c]);
        }
#pragma unroll
        for (int t = 0; t < 8; ++t)
#pragma unroll
            for (int j = 0; j < 8; ++j) a[j] += bf2f(v[t][j]);
        p += 8;
    }
    int rem = n - p;
    if (rem > 0) {
        us8 v[7];
#pragma unroll
        for (int t = 0; t < 7; ++t) {
            int s = (t < rem) ? row[p + t] : row[p];
            v[t] = *reinterpret_cast<const us8*>(&g[(size_t)s * 64 + c]);
        }
#pragma unroll
        for (int t = 0; t < 7; ++t) {
            if (t < rem) {
#pragma unroll
                for (int j = 0; j < 8; ++j) a[j] += bf2f(v[t][j]);
            }
        }
    }
    float* po = out + (size_t)node * C_OUT;
#pragma unroll
    for (int j = 0; j < 8; ++j) {
        if (c + j < C_OUT) po[c + j] += a[j];
    }
}

// ---------------- GEMM1: 512 threads, tile 128x256, 8 waves (2x4), acc[4][4]/wave ----------------
__global__ __launch_bounds__(512) void gemm1_512(
    const ushort* __restrict__ A, const ushort* __restrict__ B,
    const float* __restrict__ bias, ushort* __restrict__ hOut) {
    __shared__ alignas(16) ushort As[128 * 32];   // 8 KB
    __shared__ alignas(16) ushort Bs[256 * 32];   // 16 KB
    const int tid = threadIdx.x;
    const int lane = tid & 63, wid = tid >> 6;
    const int wr = wid >> 2, wc = wid & 3;        // 2 x 4 waves
    const int brow = blockIdx.x;

    f32x4 acc[4][4];
#pragma unroll
    for (int m = 0; m < 4; ++m)
#pragma unroll
        for (int n = 0; n < 4; ++n) acc[m][n] = (f32x4){0.f, 0.f, 0.f, 0.f};

    const int rA = tid >> 2,          kA = (tid & 3) * 8;
    const int cB1 = tid + 512;
    const int rB1 = cB1 >> 2,         kB1 = (cB1 & 3) * 8;
    const size_t aRow = (size_t)(brow * 128 + rA) * 256;

    const int aoffA = (lane & 15) * 32 + (lane >> 4) * 8;

    for (int kt = 0; kt < 8; ++kt) {
        const int kOff = kt * 32;
        load_lds16(A + aRow + kOff + kA, &As[tid * 8]);
        load_lds16(B + (size_t)rA * 256 + kOff + kA, &Bs[tid * 8]);
        load_lds16(B + (size_t)rB1 * 256 + kOff + kB1, &Bs[cB1 * 8]);
        __syncthreads();

        short8 af[4], bfr[4];
#pragma unroll
        for (int m = 0; m < 4; ++m)
            af[m] = *reinterpret_cast<const short8*>(&As[(wr * 64 + m * 16) * 32 + aoffA]);
#pragma unroll
        for (int n = 0; n < 4; ++n)
            bfr[n] = *reinterpret_cast<const short8*>(&Bs[(wc * 64 + n * 16) * 32 + aoffA]);
#pragma unroll
        for (int m = 0; m < 4; ++m)
#pragma unroll
            for (int n = 0; n < 4; ++n)
                acc[m][n] = __builtin_amdgcn_mfma_f32_16x16x32_bf16(af[m], bfr[n], acc[m][n], 0, 0, 0);
        __syncthreads();
    }

    const int colB = wc * 64 + (lane & 15);
    const int rowB = brow * 128 + wr * 64 + ((lane >> 4) << 2);

    float bv[4];
#pragma unroll
    for (int n = 0; n < 4; ++n) bv[n] = bias[colB + n * 16];
#pragma unroll
    for (int m = 0; m < 4; ++m) {
#pragma unroll
        for (int r = 0; r < 4; ++r) {
            int row = rowB + m * 16 + r;
            if (row >= N_NODES) continue;
#pragma unroll
            for (int n = 0; n < 4; ++n) {
                float v = acc[m][n][r] + bv[n];
                v = v > 0.f ? v : 0.f;
                hOut[(size_t)row * 256 + colB + n * 16] = f2bf(v);
            }
        }
    }
}

// ---------------- GEMM2: [g(bf16,stride64) | out_pre] = h @ B2t^T (+b2l) ----------------
__global__ __launch_bounds__(256) void gemm2_kernel(
    const ushort* __restrict__ A, const ushort* __restrict__ B,
    const float* __restrict__ bias, ushort* __restrict__ gOut,
    float* __restrict__ oOut) {
    __shared__ alignas(16) ushort As[128 * 32];
    __shared__ alignas(16) ushort Bs[128 * 32];
    const int tid = threadIdx.x;
    const int lane = tid & 63, wid = tid >> 6;
    const int wr = wid >> 1, wc = wid & 1;
    const int brow = blockIdx.x;

    f32x4 acc[4][4];
#pragma unroll
    for (int m = 0; m < 4; ++m)
#pragma unroll
        for (int n = 0; n < 4; ++n) acc[m][n] = (f32x4){0.f, 0.f, 0.f, 0.f};

    const int c0 = tid, c1 = tid + 256;
    const int r0 = c0 >> 2, k80 = (c0 & 3) * 8;
    const int r1 = c1 >> 2, k81 = (c1 & 3) * 8;
    const size_t aRow0 = (size_t)(brow * 128 + r0) * 256;
    const size_t aRow1 = (size_t)(brow * 128 + r1) * 256;
    const size_t bRow0 = (size_t)r0 * 256;
    const size_t bRow1 = (size_t)r1 * 256;

    const int aoffA = (lane & 15) * 32 + (lane >> 4) * 8;

    for (int kt = 0; kt < 8; ++kt) {
        const int kOff = kt * 32;
        load_lds16(A + aRow0 + kOff + k80, &As[c0 * 8]);
        load_lds16(A + aRow1 + kOff + k81, &As[c1 * 8]);
        load_lds16(B + bRow0 + kOff + k80, &Bs[c0 * 8]);
        load_lds16(B + bRow1 + kOff + k81, &Bs[c1 * 8]);
        __syncthreads();

        short8 af[4], bfr[4];
#pragma unroll
        for (int m = 0; m < 4; ++m)
            af[m] = *reinterpret_cast<const short8*>(&As[(wr * 64 + m * 16) * 32 + aoffA]);
#pragma unroll
        for (int n = 0; n < 4; ++n)
            bfr[n] = *reinterpret_cast<const short8*>(&Bs[(wc * 64 + n * 16) * 32 + aoffA]);
#pragma unroll
        for (int m = 0; m < 4; ++m)
#pragma unroll
            for (int n = 0; n < 4; ++n)
                acc[m][n] = __builtin_amdgcn_mfma_f32_16x16x32_bf16(af[m], bfr[n], acc[m][n], 0, 0, 0);
        __syncthreads();
    }

    const int colB = wc * 64 + (lane & 15);
    const int rowB = brow * 128 + wr * 64 + ((lane >> 4) << 2);

#pragma unroll
    for (int m = 0; m < 4; ++m) {
#pragma unroll
        for (int r = 0; r < 4; ++r) {
            int row = rowB + m * 16 + r;
            if (row >= N_NODES) continue;
#pragma unroll
            for (int n = 0; n < 4; ++n) {
                int cg = colB + n * 16;
                float v = acc[m][n][r];
                if (cg < 64) {
                    gOut[(size_t)row * 64 + cg] = f2bf(v);
                } else if (cg < 64 + C_OUT) {
                    oOut[(size_t)row * C_OUT + (cg - 64)] = v + bias[cg - 64];
                }
            }
        }
    }
}

extern "C" void kernel_launch(void* const* d_in, const int* in_sizes, int n_in,
                              void* d_out, int out_size, void* d_ws, size_t ws_size,
                              hipStream_t stream) {
    const float* x   = (const float*)d_in[0];
    const int*   ei  = (const int*)d_in[1];
    const float* W1l = (const float*)d_in[2];
    const float* b1l = (const float*)d_in[3];
    const float* W1r = (const float*)d_in[4];
    const float* W2l = (const float*)d_in[5];
    const float* b2l = (const float*)d_in[6];
    const float* W2r = (const float*)d_in[7];
    float* out = (float*)d_out;

    ushort* A1    = (ushort*)d_ws;                        // MPAD*256 bf16
    ushort* hbuf  = A1 + (size_t)MPAD * 256;              // MPAD*256 bf16
    ushort* B1t   = hbuf + (size_t)MPAD * 256;            // 256*256 bf16
    ushort* B2t   = B1t + 256 * 256;                      // 128*256 bf16
    ushort* g     = B2t + 128 * 256;                      // N*64 bf16
    int* cnt      = (int*)(g + (size_t)N_NODES * 64);     // N
    int* bucket   = cnt + N_NODES;                        // N*CAP
    int* cnt1     = bucket + (size_t)N_NODES * CAP;       // NRANGE*P1BLK
    int* subbucket= cnt1 + NRANGE * P1BLK;                // NRANGE*P1BLK*CCAP

    const int* src = ei;
    const int* dst = ei + N_EDGES;

    phase1_xcvt<<<P1BLK + XBLK + WBLK, 256, 0, stream>>>(
        src, dst, cnt1, subbucket, x, A1, W1l, W1r, W2l, W2r, B1t, B2t);
    phase2_merge<<<NRANGE, 256, 0, stream>>>(cnt1, subbucket, cnt, bucket);

    gather1_kernel<<<(N_NODES * 8 + 255) / 256, 256, 0, stream>>>(cnt, bucket, A1);

    const int nbrow = MPAD / 128;  // 782
    gemm1_512<<<nbrow, 512, 0, stream>>>(A1, B1t, b1l, hbuf);
    gemm2_kernel<<<nbrow, 256, 0, stream>>>(hbuf, B2t, b2l, g, out);

    gather2_kernel<<<(N_NODES * 8 + 255) / 256, 256, 0, stream>>>(g, cnt, bucket, out);
}

// Round 16
// 147.322 us; speedup vs baseline: 1.1838x; 1.0007x over previous
//
#include <hip/hip_runtime.h>

#define N_NODES 100000
#define MPAD    100096   // 782*128
#define F_IN 128
#define HID 256
#define C_OUT 50
#define N_EDGES 640000
#define CAP 32           // per-node bucket capacity (max degree ~22)
#define NRANGE 391       // ceil(N/256) node ranges of 256
#define P1BLK 256        // phase-1 blocks
#define EPB (N_EDGES / P1BLK)   // 2500 edges per phase-1 block
#define CCAP 32          // per (range, block) cell capacity (mean 6.4)
#define XBLK 12500       // xcvt blocks
#define WBLK 256         // weight-pack blocks

typedef __attribute__((ext_vector_type(8))) short short8;
typedef __attribute__((ext_vector_type(8))) ushort us8;
typedef __attribute__((ext_vector_type(4))) float f32x4;

struct alignas(8) us4 { ushort x, y, z, w; };

__device__ __forceinline__ ushort f2bf(float f) {
    union { float f; unsigned u; } v; v.f = f;
    unsigned r = (v.u + 0x7fffu + ((v.u >> 16) & 1u)) >> 16;  // RNE
    return (ushort)r;
}

__device__ __forceinline__ float bf2f(ushort u) {
    union { unsigned u; float f; } v; v.u = ((unsigned)u) << 16;
    return v.f;
}

__device__ __forceinline__ void load_lds16(const void* gsrc, void* lds) {
    __builtin_amdgcn_global_load_lds(
        (const __attribute__((address_space(1))) void*)gsrc,
        (__attribute__((address_space(3))) void*)lds, 16, 0, 0);
}

// ---------------- fused: edge phase 1 || xcvt || weight pack ----------------
__global__ __launch_bounds__(256) void phase1_xcvt(const int* __restrict__ src,
                                                   const int* __restrict__ dst,
                                                   int* __restrict__ cnt1,
                                                   int* __restrict__ subbucket,
                                                   const float* __restrict__ x,
                                                   ushort* __restrict__ A1,
                                                   const float* __restrict__ W1l,
                                                   const float* __restrict__ W1r,
                                                   const float* __restrict__ W2l,
                                                   const float* __restrict__ W2r,
                                                   ushort* __restrict__ B1t,
                                                   ushort* __restrict__ B2t) {
    __shared__ int lcnt[NRANGE];
    int b = blockIdx.x;
    if (b < P1BLK) {
        for (int r = threadIdx.x; r < NRANGE; r += 256) lcnt[r] = 0;
        __syncthreads();
        int base = b * EPB;
        for (int i = base + (int)threadIdx.x; i < base + EPB; i += 256) {
            int d = dst[i];
            int s = src[i];
            int r = d >> 8;
            int p = atomicAdd(&lcnt[r], 1);
            if (p < CCAP) subbucket[((size_t)r * P1BLK + b) * CCAP + p] = ((d & 255) << 24) | s;
        }
        __syncthreads();
        for (int r = threadIdx.x; r < NRANGE; r += 256) cnt1[r * P1BLK + b] = lcnt[r];
    } else if (b < P1BLK + XBLK) {
        int tid = (b - P1BLK) * 256 + threadIdx.x;
        int node = tid >> 5, q = tid & 31;
        if (node >= N_NODES) return;
        float4 v = *reinterpret_cast<const float4*>(x + (size_t)node * F_IN + q * 4);
        us4 o;
        o.x = f2bf(v.x); o.y = f2bf(v.y); o.z = f2bf(v.z); o.w = f2bf(v.w);
        *reinterpret_cast<us4*>(&A1[(size_t)node * 256 + 128 + q * 4]) = o;
    } else {
        int idx = (b - P1BLK - XBLK) * 256 + threadIdx.x;
        if (idx < 256 * 256) {
            int o = idx >> 8, k = idx & 255;
            float v = (k < 128) ? W1l[o * 128 + k] : W1r[o * 128 + (k - 128)];
            B1t[o * 256 + k] = f2bf(v);
        }
        if (idx < 128 * 256) {
            int c = idx >> 8, k = idx & 255;
            float v = 0.f;
            if (c < C_OUT) v = W2l[c * 256 + k];
            else if (c >= 64 && c < 64 + C_OUT) v = W2r[(c - 64) * 256 + k];
            B2t[c * 256 + k] = f2bf(v);
        }
    }
}

// ---------------- edge phase 2: merge cells -> per-node buckets (coalesced out) ----------------
__global__ __launch_bounds__(256) void phase2_merge(const int* __restrict__ cnt1,
                                                    const int* __restrict__ subbucket,
                                                    int* __restrict__ cnt,
                                                    int* __restrict__ bucket) {
    __shared__ int lcnt2[256];
    __shared__ int lbuf[256 * CAP];  // 32 KB
    int r = blockIdx.x, t = threadIdx.x;
    lcnt2[t] = 0;
    __syncthreads();
    int n = cnt1[r * P1BLK + t];
    if (n > CCAP) n = CCAP;
    size_t cbase = ((size_t)r * P1BLK + t) * CCAP;
    for (int k = 0; k < n; ++k) {
        unsigned u = (unsigned)subbucket[cbase + k];
        int dl = u >> 24;
        int p = atomicAdd(&lcnt2[dl], 1);
        if (p < CAP) lbuf[dl * CAP + p] = (int)(u & 0xFFFFFF);
    }
    __syncthreads();
    int node0 = r << 8;
    if (node0 + t < N_NODES) cnt[node0 + t] = lcnt2[t];
    for (int idx = t; idx < 256 * CAP; idx += 256) {
        if (node0 + (idx >> 5) < N_NODES) bucket[(size_t)node0 * CAP + idx] = lbuf[idx];
    }
}

// ---------------- gather1: A1[i][0..127] = bf16( sum_{s in N(i)} bf16x[s] ) ----------------
// 8 lanes/node, 32 B/neighbor. Fast path n<=7 (70% of nodes): ONE latency round with
// all 14 dwordx4 loads in flight. Else batch-4 loop + predicated tail-3.
__global__ void gather1_kernel(const int* __restrict__ cnt, const int* __restrict__ bucket,
                               ushort* __restrict__ A1) {
    int tid = blockIdx.x * blockDim.x + threadIdx.x;
    int node = tid >> 3, q = tid & 7;
    if (node >= N_NODES) return;
    int n = cnt[node];
    if (n > CAP) n = CAP;
    const int* row = bucket + (size_t)node * CAP;
    float a[16];
#pragma unroll
    for (int j = 0; j < 16; ++j) a[j] = 0.f;

    if (n > 0 && n <= 7) {
        us8 v0[7], v1[7];
#pragma unroll
        for (int t = 0; t < 7; ++t) {
            int s = (t < n) ? row[t] : row[0];
            const ushort* base = &A1[(size_t)s * 256 + 128 + q * 16];
            v0[t] = *reinterpret_cast<const us8*>(base);
            v1[t] = *reinterpret_cast<const us8*>(base + 8);
        }
#pragma unroll
        for (int t = 0; t < 7; ++t) {
            if (t < n) {
#pragma unroll
                for (int j = 0; j < 8; ++j) a[j] += bf2f(v0[t][j]);
#pragma unroll
                for (int j = 0; j < 8; ++j) a[8 + j] += bf2f(v1[t][j]);
            }
        }
    } else if (n > 7) {
        int p = 0;
        while (p + 4 <= n) {
            us8 v0[4], v1[4];
#pragma unroll
            for (int t = 0; t < 4; ++t) {
                const ushort* base = &A1[(size_t)row[p + t] * 256 + 128 + q * 16];
                v0[t] = *reinterpret_cast<const us8*>(base);
                v1[t] = *reinterpret_cast<const us8*>(base + 8);
            }
#pragma unroll
            for (int t = 0; t < 4; ++t) {
#pragma unroll
                for (int j = 0; j < 8; ++j) a[j] += bf2f(v0[t][j]);
#pragma unroll
                for (int j = 0; j < 8; ++j) a[8 + j] += bf2f(v1[t][j]);
            }
            p += 4;
        }
        int rem = n - p;
        if (rem > 0) {
            us8 v0[3], v1[3];
#pragma unroll
            for (int t = 0; t < 3; ++t) {
                int s = (t < rem) ? row[p + t] : row[p];
                const ushort* base = &A1[(size_t)s * 256 + 128 + q * 16];
                v0[t] = *reinterpret_cast<const us8*>(base);
                v1[t] = *reinterpret_cast<const us8*>(base + 8);
            }
#pragma unroll
            for (int t = 0; t < 3; ++t) {
                if (t < rem) {
#pragma unroll
                    for (int j = 0; j < 8; ++j) a[j] += bf2f(v0[t][j]);
#pragma unroll
                    for (int j = 0; j < 8; ++j) a[8 + j] += bf2f(v1[t][j]);
                }
            }
        }
    }

    us8 o0, o1;
#pragma unroll
    for (int j = 0; j < 8; ++j) { o0[j] = f2bf(a[j]); o1[j] = f2bf(a[8 + j]); }
    ushort* wbase = &A1[(size_t)node * 256 + q * 16];
    *reinterpret_cast<us8*>(wbase) = o0;
    *reinterpret_cast<us8*>(wbase + 8) = o1;
}

// ---------------- gather2: out[i] += sum_{s in N(i)} g[s] (g bf16, stride 64) ----------------
__global__ void gather2_kernel(const ushort* __restrict__ g, const int* __restrict__ cnt,
                               const int* __restrict__ bucket, float* __restrict__ out) {
    int tid = blockIdx.x * blockDim.x + threadIdx.x;
    int node = tid >> 3, q = tid & 7;
    if (node >= N_NODES) return;
    int c = q * 8;
    if (c >= C_OUT) return;
    int n = cnt[node];
    if (n > CAP) n = CAP;
    const int* row = bucket + (size_t)node * CAP;
    float a[8];
#pragma unroll
    for (int j = 0; j < 8; ++j) a[j] = 0.f;
    int p = 0;
    while (p + 8 <= n) {
        us8 v[8];
#pragma unroll
        for (int t = 0; t < 8; ++t) {
            int s = row[p + t];
            v[t] = *reinterpret_cast<const us8*>(&g[(size_t)s * 64 + c]);
        }
#pragma unroll
        for (int t = 0; t < 8; ++t)
#pragma unroll
            for (int j = 0; j < 8; ++j) a[j] += bf2f(v[t][j]);
        p += 8;
    }
    int rem = n - p;
    if (rem > 0) {
        us8 v[7];
#pragma unroll
        for (int t = 0; t < 7; ++t) {
            int s = (t < rem) ? row[p + t] : row[p];
            v[t] = *reinterpret_cast<const us8*>(&g[(size_t)s * 64 + c]);
        }
#pragma unroll
        for (int t = 0; t < 7; ++t) {
            if (t < rem) {
#pragma unroll
                for (int j = 0; j < 8; ++j) a[j] += bf2f(v[t][j]);
            }
        }
    }
    float* po = out + (size_t)node * C_OUT;
#pragma unroll
    for (int j = 0; j < 8; ++j) {
        if (c + j < C_OUT) po[c + j] += a[j];
    }
}

// ---------------- GEMM1: 512 threads, tile 128x256, 8 waves (2x4), acc[4][4]/wave ----------------
__global__ __launch_bounds__(512) void gemm1_512(
    const ushort* __restrict__ A, const ushort* __restrict__ B,
    const float* __restrict__ bias, ushort* __restrict__ hOut) {
    __shared__ alignas(16) ushort As[128 * 32];   // 8 KB
    __shared__ alignas(16) ushort Bs[256 * 32];   // 16 KB
    const int tid = threadIdx.x;
    const int lane = tid & 63, wid = tid >> 6;
    const int wr = wid >> 2, wc = wid & 3;        // 2 x 4 waves
    const int brow = blockIdx.x;

    f32x4 acc[4][4];
#pragma unroll
    for (int m = 0; m < 4; ++m)
#pragma unroll
        for (int n = 0; n < 4; ++n) acc[m][n] = (f32x4){0.f, 0.f, 0.f, 0.f};

    const int rA = tid >> 2,          kA = (tid & 3) * 8;
    const int cB1 = tid + 512;
    const int rB1 = cB1 >> 2,         kB1 = (cB1 & 3) * 8;
    const size_t aRow = (size_t)(brow * 128 + rA) * 256;

    const int aoffA = (lane & 15) * 32 + (lane >> 4) * 8;

    for (int kt = 0; kt < 8; ++kt) {
        const int kOff = kt * 32;
        load_lds16(A + aRow + kOff + kA, &As[tid * 8]);
        load_lds16(B + (size_t)rA * 256 + kOff + kA, &Bs[tid * 8]);
        load_lds16(B + (size_t)rB1 * 256 + kOff + kB1, &Bs[cB1 * 8]);
        __syncthreads();

        short8 af[4], bfr[4];
#pragma unroll
        for (int m = 0; m < 4; ++m)
            af[m] = *reinterpret_cast<const short8*>(&As[(wr * 64 + m * 16) * 32 + aoffA]);
#pragma unroll
        for (int n = 0; n < 4; ++n)
            bfr[n] = *reinterpret_cast<const short8*>(&Bs[(wc * 64 + n * 16) * 32 + aoffA]);
#pragma unroll
        for (int m = 0; m < 4; ++m)
#pragma unroll
            for (int n = 0; n < 4; ++n)
                acc[m][n] = __builtin_amdgcn_mfma_f32_16x16x32_bf16(af[m], bfr[n], acc[m][n], 0, 0, 0);
        __syncthreads();
    }

    const int colB = wc * 64 + (lane & 15);
    const int rowB = brow * 128 + wr * 64 + ((lane >> 4) << 2);

    float bv[4];
#pragma unroll
    for (int n = 0; n < 4; ++n) bv[n] = bias[colB + n * 16];
#pragma unroll
    for (int m = 0; m < 4; ++m) {
#pragma unroll
        for (int r = 0; r < 4; ++r) {
            int row = rowB + m * 16 + r;
            if (row >= N_NODES) continue;
#pragma unroll
            for (int n = 0; n < 4; ++n) {
                float v = acc[m][n][r] + bv[n];
                v = v > 0.f ? v : 0.f;
                hOut[(size_t)row * 256 + colB + n * 16] = f2bf(v);
            }
        }
    }
}

// ---------------- GEMM2: [g(bf16,stride64) | out_pre] = h @ B2t^T (+b2l) ----------------
__global__ __launch_bounds__(256) void gemm2_kernel(
    const ushort* __restrict__ A, const ushort* __restrict__ B,
    const float* __restrict__ bias, ushort* __restrict__ gOut,
    float* __restrict__ oOut) {
    __shared__ alignas(16) ushort As[128 * 32];
    __shared__ alignas(16) ushort Bs[128 * 32];
    const int tid = threadIdx.x;
    const int lane = tid & 63, wid = tid >> 6;
    const int wr = wid >> 1, wc = wid & 1;
    const int brow = blockIdx.x;

    f32x4 acc[4][4];
#pragma unroll
    for (int m = 0; m < 4; ++m)
#pragma unroll
        for (int n = 0; n < 4; ++n) acc[m][n] = (f32x4){0.f, 0.f, 0.f, 0.f};

    const int c0 = tid, c1 = tid + 256;
    const int r0 = c0 >> 2, k80 = (c0 & 3) * 8;
    const int r1 = c1 >> 2, k81 = (c1 & 3) * 8;
    const size_t aRow0 = (size_t)(brow * 128 + r0) * 256;
    const size_t aRow1 = (size_t)(brow * 128 + r1) * 256;
    const size_t bRow0 = (size_t)r0 * 256;
    const size_t bRow1 = (size_t)r1 * 256;

    const int aoffA = (lane & 15) * 32 + (lane >> 4) * 8;

    for (int kt = 0; kt < 8; ++kt) {
        const int kOff = kt * 32;
        load_lds16(A + aRow0 + kOff + k80, &As[c0 * 8]);
        load_lds16(A + aRow1 + kOff + k81, &As[c1 * 8]);
        load_lds16(B + bRow0 + kOff + k80, &Bs[c0 * 8]);
        load_lds16(B + bRow1 + kOff + k81, &Bs[c1 * 8]);
        __syncthreads();

        short8 af[4], bfr[4];
#pragma unroll
        for (int m = 0; m < 4; ++m)
            af[m] = *reinterpret_cast<const short8*>(&As[(wr * 64 + m * 16) * 32 + aoffA]);
#pragma unroll
        for (int n = 0; n < 4; ++n)
            bfr[n] = *reinterpret_cast<const short8*>(&Bs[(wc * 64 + n * 16) * 32 + aoffA]);
#pragma unroll
        for (int m = 0; m < 4; ++m)
#pragma unroll
            for (int n = 0; n < 4; ++n)
                acc[m][n] = __builtin_amdgcn_mfma_f32_16x16x32_bf16(af[m], bfr[n], acc[m][n], 0, 0, 0);
        __syncthreads();
    }

    const int colB = wc * 64 + (lane & 15);
    const int rowB = brow * 128 + wr * 64 + ((lane >> 4) << 2);

#pragma unroll
    for (int m = 0; m < 4; ++m) {
#pragma unroll
        for (int r = 0; r < 4; ++r) {
            int row = rowB + m * 16 + r;
            if (row >= N_NODES) continue;
#pragma unroll
            for (int n = 0; n < 4; ++n) {
                int cg = colB + n * 16;
                float v = acc[m][n][r];
                if (cg < 64) {
                    gOut[(size_t)row * 64 + cg] = f2bf(v);
                } else if (cg < 64 + C_OUT) {
                    oOut[(size_t)row * C_OUT + (cg - 64)] = v + bias[cg - 64];
                }
            }
        }
    }
}

extern "C" void kernel_launch(void* const* d_in, const int* in_sizes, int n_in,
                              void* d_out, int out_size, void* d_ws, size_t ws_size,
                              hipStream_t stream) {
    const float* x   = (const float*)d_in[0];
    const int*   ei  = (const int*)d_in[1];
    const float* W1l = (const float*)d_in[2];
    const float* b1l = (const float*)d_in[3];
    const float* W1r = (const float*)d_in[4];
    const float* W2l = (const float*)d_in[5];
    const float* b2l = (const float*)d_in[6];
    const float* W2r = (const float*)d_in[7];
    float* out = (float*)d_out;

    ushort* A1    = (ushort*)d_ws;                        // MPAD*256 bf16
    ushort* hbuf  = A1 + (size_t)MPAD * 256;              // MPAD*256 bf16
    ushort* B1t   = hbuf + (size_t)MPAD * 256;            // 256*256 bf16
    ushort* B2t   = B1t + 256 * 256;                      // 128*256 bf16
    ushort* g     = B2t + 128 * 256;                      // N*64 bf16
    int* cnt      = (int*)(g + (size_t)N_NODES * 64);     // N
    int* bucket   = cnt + N_NODES;                        // N*CAP
    int* cnt1     = bucket + (size_t)N_NODES * CAP;       // NRANGE*P1BLK
    int* subbucket= cnt1 + NRANGE * P1BLK;                // NRANGE*P1BLK*CCAP

    const int* src = ei;
    const int* dst = ei + N_EDGES;

    phase1_xcvt<<<P1BLK + XBLK + WBLK, 256, 0, stream>>>(
        src, dst, cnt1, subbucket, x, A1, W1l, W1r, W2l, W2r, B1t, B2t);
    phase2_merge<<<NRANGE, 256, 0, stream>>>(cnt1, subbucket, cnt, bucket);

    gather1_kernel<<<(N_NODES * 8 + 255) / 256, 256, 0, stream>>>(cnt, bucket, A1);

    const int nbrow = MPAD / 128;  // 782
    gemm1_512<<<nbrow, 512, 0, stream>>>(A1, B1t, b1l, hbuf);
    gemm2_kernel<<<nbrow, 256, 0, stream>>>(hbuf, B2t, b2l, g, out);

    gather2_kernel<<<(N_NODES * 8 + 255) / 256, 256, 0, stream>>>(g, cnt, bucket, out);
}